// Round 6
// baseline (1083.670 us; speedup 1.0000x reference)
//
#include <hip/hip_runtime.h>
#include <hip/hip_bf16.h>

using bf16 = __hip_bfloat16;
typedef short bf16x8 __attribute__((ext_vector_type(8)));
typedef float f32x4  __attribute__((ext_vector_type(4)));
typedef unsigned short u16;

__device__ __forceinline__ float leakyf(float x) { return x >= 0.f ? x : 0.01f * x; }

__device__ __forceinline__ float b2f(u16 u) {
  union { unsigned int i; float f; } c; c.i = (unsigned int)u << 16; return c.f;
}
__device__ __forceinline__ u16 f2b(float f) {
  __hip_bfloat16 h = __float2bfloat16(f);
  return *reinterpret_cast<u16*>(&h);
}
__device__ __forceinline__ ushort4 pack4(float a, float b, float c, float d) {
  ushort4 u; u.x = f2b(a); u.y = f2b(b); u.z = f2b(c); u.w = f2b(d); return u;
}

// B-fragment straight from global (prepacked granule order): one dwordx4/lane
__device__ __forceinline__ bf16x8 gfrag(const bf16* __restrict__ p, int gran) {
  return *(const bf16x8*)(p + ((size_t)gran << 3));
}
// A-fragment from XOR-swizzled [128][64] bf16 sub-pane (stride 128 B)
__device__ __forceinline__ bf16x8 ldsRow(const short* buf, int row, int off) {
  return *(const bf16x8*)((const char*)buf + row * 128 + (off ^ ((row & 7) << 4)));
}
// scatter/gather one C-frag column quad (4 consecutive rows), swizzled pane
__device__ __forceinline__ void scat4(short* base, int row0, int col2, ushort4 q) {
  *(u16*)((char*)base + (row0 + 0) * 128 + (col2 ^ (((row0 + 0) & 7) << 4))) = q.x;
  *(u16*)((char*)base + (row0 + 1) * 128 + (col2 ^ (((row0 + 1) & 7) << 4))) = q.y;
  *(u16*)((char*)base + (row0 + 2) * 128 + (col2 ^ (((row0 + 2) & 7) << 4))) = q.z;
  *(u16*)((char*)base + (row0 + 3) * 128 + (col2 ^ (((row0 + 3) & 7) << 4))) = q.w;
}
__device__ __forceinline__ ushort4 gath4(const short* base, int row0, int col2) {
  ushort4 q;
  q.x = *(const u16*)((const char*)base + (row0 + 0) * 128 + (col2 ^ (((row0 + 0) & 7) << 4)));
  q.y = *(const u16*)((const char*)base + (row0 + 1) * 128 + (col2 ^ (((row0 + 1) & 7) << 4)));
  q.z = *(const u16*)((const char*)base + (row0 + 2) * 128 + (col2 ^ (((row0 + 2) & 7) << 4)));
  q.w = *(const u16*)((const char*)base + (row0 + 3) * 128 + (col2 ^ (((row0 + 3) & 7) << 4)));
  return q;
}

// f32 dot: w from global (L2-resident), x from LDS, K4 = K/4
__device__ __forceinline__ float dotW(const float* __restrict__ w,
                                      const float* __restrict__ x, int K4) {
  float s = 0.f;
#pragma unroll 4
  for (int i = 0; i < K4; ++i) {
    float4 wv = *(const float4*)(w + i * 4);
    s += wv.x * x[i * 4 + 0] + wv.y * x[i * 4 + 1] +
         wv.z * x[i * 4 + 2] + wv.w * x[i * 4 + 3];
  }
  return s;
}

// ---------------------------------------------------------------------------
// MFMA weight prepack: fp32 [K][Nc] row-major -> bf16 fragment granules
// granule f = ((ks*NTN + nt)*8 + ch)*16 + i holds cols nt*16+i, k = ks*64+ch*8..+7
// ---------------------------------------------------------------------------
__global__ void pack_tiles(const float* __restrict__ pu1, const float* __restrict__ pu2,
                           const float* __restrict__ cw,
                           bf16* __restrict__ W0, bf16* __restrict__ W1t,
                           bf16* __restrict__ W4) {
  int job = blockIdx.y, type = job / 3, l = job % 3;
  int f = blockIdx.x * 256 + threadIdx.x;
  const float* s; bf16* d; int ld, nch, ntn;
  if (type == 0)      { nch = 25600; s = pu1 + (size_t)l * 204800; d = W0  + (size_t)l * 204800; ld = 640; ntn = 40; }
  else if (type == 1) { nch = 25600; s = pu2 + (size_t)l * 204800; d = W1t + (size_t)l * 204800; ld = 320; ntn = 20; }
  else                { nch = 12800; s = cw  + (size_t)l * 204800; d = W4  + (size_t)l * 102400; ld = 320; ntn = 20; }
  if (f >= nch) return;
  int i = f & 15, ch = (f >> 4) & 7, nt = (f >> 7) % ntn, ks = (f >> 7) / ntn;
  int k = ks * 64 + ch * 8, col = nt * 16 + i;
  bf16x8 v;
#pragma unroll
  for (int j = 0; j < 8; ++j)
    v[j] = (short)f2b(s[(size_t)(k + j) * ld + col]);
  *(bf16x8*)(d + (size_t)f * 8) = v;
}

// ---------------------------------------------------------------------------
// GEMV weight prepack (n-major, f32): out[n][k] = src[k][n]
// jobs 0-2 Wg1 (gu_W1 K320 N640) 3-5 Wg2 (gu_W2 K640 N320)
//      6-8 Wg3 (c_W rows 320.. K320 N320) 9 Wo1 (o_W1 K320 N640)
// ---------------------------------------------------------------------------
__global__ void pack_nmaj(const float* __restrict__ gu1, const float* __restrict__ gu2,
                          const float* __restrict__ cw, const float* __restrict__ ow1,
                          float* __restrict__ Wg1, float* __restrict__ Wg2,
                          float* __restrict__ Wg3, float* __restrict__ Wo1) {
  int job = blockIdx.y;
  int f = blockIdx.x * 256 + threadIdx.x;
  const float* s; float* d; int K, ld, nch, koff = 0;
  if (job < 3)      { int l = job;     K = 320; ld = 640; nch = 51200; s = gu1 + (size_t)l * 204800; d = Wg1 + (size_t)l * 204800; }
  else if (job < 6) { int l = job - 3; K = 640; ld = 320; nch = 51200; s = gu2 + (size_t)l * 204800; d = Wg2 + (size_t)l * 204800; }
  else if (job < 9) { int l = job - 6; K = 320; ld = 320; nch = 25600; s = cw  + (size_t)l * 204800; d = Wg3 + (size_t)l * 102400; koff = 320; }
  else              {                  K = 320; ld = 640; nch = 51200; s = ow1;                      d = Wo1; }
  if (f >= nch) return;
  int K4 = K >> 2;
  int n = f / K4, kq = f % K4;
  int k = koff + kq * 4;
  float4 v = { s[(size_t)(k + 0) * ld + n], s[(size_t)(k + 1) * ld + n],
               s[(size_t)(k + 2) * ld + n], s[(size_t)(k + 3) * ld + n] };
  *(float4*)(d + (size_t)f * 4) = v;
}

#define MFMA_BF16 __builtin_amdgcn_mfma_f32_16x16x32_bf16

// ---------------------------------------------------------------------------
// Fused per-group network. Block = 1 group (128 rows), 256 thr = 4 waves (2r x 2c).
// 1 wave/SIMD (launch_bounds(256,1)) -> 512-reg budget: acc2[4][10]+hf[4][10]
// fit with slack -> no spills. Abuf[5][128][64]: resident `out` (XOR-swizzled).
// h1/h flow through pane[2][128][64]. GEMV weights f32 n-major (no converts).
// All MFMA B-operands load as granules directly from L2 (prepacked order).
// ---------------------------------------------------------------------------
__global__ __launch_bounds__(256, 1)
void fused_k(const int* __restrict__ words, const int* __restrict__ lengths,
             const float* __restrict__ embed,
             const bf16* __restrict__ W0, const bf16* __restrict__ W1t,
             const bf16* __restrict__ W4,
             const float* __restrict__ Wg1, const float* __restrict__ Wg2,
             const float* __restrict__ Wg3, const float* __restrict__ Wo1,
             const float* __restrict__ pb1, const float* __restrict__ pb2,
             const float* __restrict__ gb1, const float* __restrict__ gb2,
             const float* __restrict__ cb,  const float* __restrict__ ob1,
             const float* __restrict__ oW2, const float* __restrict__ ob2,
             const float* __restrict__ wsc, float* __restrict__ yout)
{
  __shared__ short Abuf[5][8192];   // 80 KB resident out
  __shared__ short pane[2][8192];   // 32 KB h1/h chunk dbuf
  __shared__ int   wrdL[640];
  __shared__ float mvec[320], gvec[320];
  __shared__ float tvec[640], pbuf[640];
  __shared__ float redH[4];

  const int g    = blockIdx.x;
  const int tid  = threadIdx.x;
  const int wave = tid >> 6, lane = tid & 63;
  const int r    = wave >> 1, wc = wave & 1;   // 2 row-waves x 2 col-waves
  const int i16  = lane & 15, kg = lane >> 4;
  const int r64  = r * 64;
  const float invLen = 1.0f / (float)lengths[g];

  for (int i = tid; i < 640; i += 256) wrdL[i] = words[(size_t)g * 640 + i];
  __syncthreads();

  // ---- init Abuf = embedded points (bf16, swizzled sub-panes) ----
#pragma unroll
  for (int q = 0; q < 20; ++q) {
    int f = q * 256 + tid;               // 5120 chunks: 128 rows x 40 col-chunks
    int row = f / 40, cc = f - row * 40;
    int sub = cc >> 3, lc = cc & 7;
    int col0 = cc * 8;
    int w = wrdL[row * 5 + (col0 >> 6)];
    const float* ep = embed + (size_t)w * 64 + (col0 & 63);
    bf16x8 v;
#pragma unroll
    for (int u = 0; u < 8; ++u) v[u] = (short)f2b(ep[u]);
    *(bf16x8*)((char*)(Abuf[sub]) + row * 128 + ((lc * 16) ^ ((row & 7) << 4))) = v;
  }

  ushort4 hf[4][10];

  for (int l = 0; l < 3; ++l) {
    const bf16*  W0l  = W0  + (size_t)l * 204800;
    const bf16*  W1l  = W1t + (size_t)l * 204800;
    const bf16*  W4l  = W4  + (size_t)l * 102400;
    const float* Wg1l = Wg1 + (size_t)l * 204800;
    const float* Wg2l = Wg2 + (size_t)l * 204800;
    const float* Wg3l = Wg3 + (size_t)l * 102400;

    __syncthreads();   // Abuf writes (embed / prev epilogue) + pane reuse safe

    // ============ point MLP: 10 chunks of 64 h1-cols, GEMM1 -> pane -> GEMM2
    f32x4 acc2[4][10];
#pragma unroll
    for (int m = 0; m < 4; ++m)
#pragma unroll
      for (int t = 0; t < 10; ++t) acc2[m][t] = {0.f, 0.f, 0.f, 0.f};

    for (int c = 0; c < 10; ++c) {
      short* pn = pane[c & 1];
      // GEMM1: wave's 2 tiles (c*4+wc, c*4+wc+2) of h1 = leaky(out @ W0 + b1)
      f32x4 acc1[4][2];
#pragma unroll
      for (int m = 0; m < 4; ++m) { acc1[m][0] = {0.f,0.f,0.f,0.f}; acc1[m][1] = {0.f,0.f,0.f,0.f}; }
#pragma unroll
      for (int ks = 0; ks < 5; ++ks) {
#pragma unroll
        for (int kk = 0; kk < 2; ++kk) {
          const int off = (kk * 32 + kg * 8) * 2;
          bf16x8 a[4];
#pragma unroll
          for (int m = 0; m < 4; ++m) a[m] = ldsRow(Abuf[ks], r64 + m * 16 + i16, off);
          bf16x8 b0 = gfrag(W0l, ((ks * 40 + c * 4 + wc)     * 8 + kk * 4 + kg) * 16 + i16);
          bf16x8 b1 = gfrag(W0l, ((ks * 40 + c * 4 + wc + 2) * 8 + kk * 4 + kg) * 16 + i16);
#pragma unroll
          for (int m = 0; m < 4; ++m) acc1[m][0] = MFMA_BF16(a[m], b0, acc1[m][0], 0, 0, 0);
#pragma unroll
          for (int m = 0; m < 4; ++m) acc1[m][1] = MFMA_BF16(a[m], b1, acc1[m][1], 0, 0, 0);
        }
      }
#pragma unroll
      for (int tt = 0; tt < 2; ++tt) {
        const int lt = wc + 2 * tt;                 // pane-local tile 0..3
        const float bv = pb1[l * 640 + c * 64 + lt * 16 + i16];
        const int pcol2 = (lt * 16 + i16) * 2;
#pragma unroll
        for (int m = 0; m < 4; ++m)
          scat4(pn, r64 + m * 16 + kg * 4, pcol2,
                pack4(leakyf(acc1[m][tt][0] + bv), leakyf(acc1[m][tt][1] + bv),
                      leakyf(acc1[m][tt][2] + bv), leakyf(acc1[m][tt][3] + bv)));
      }
      __syncthreads();                 // pane chunk ready (dbuf keeps 1 bar safe)
      // GEMM2 accumulate: k-slice c
#pragma unroll
      for (int kk = 0; kk < 2; ++kk) {
        const int off = (kk * 32 + kg * 8) * 2;
        bf16x8 a[4];
#pragma unroll
        for (int m = 0; m < 4; ++m) a[m] = ldsRow(pn, r64 + m * 16 + i16, off);
        bf16x8 b[10];
#pragma unroll
        for (int t = 0; t < 10; ++t)
          b[t] = gfrag(W1l, ((c * 20 + wc + 2 * t) * 8 + kk * 4 + kg) * 16 + i16);
#pragma unroll
        for (int m = 0; m < 4; ++m)
#pragma unroll
          for (int t = 0; t < 10; ++t) acc2[m][t] = MFMA_BF16(a[m], b[t], acc2[m][t], 0, 0, 0);
      }
    }

    // ============ h epilogue: hf regs + column sums -> mvec ============
#pragma unroll
    for (int t = 0; t < 10; ++t) {
      const int col = (wc + 2 * t) * 16 + i16;
      const float bv = pb2[l * 320 + col];
      float cs = 0.f;
#pragma unroll
      for (int m = 0; m < 4; ++m) {
        float v0 = leakyf(acc2[m][t][0] + bv), v1 = leakyf(acc2[m][t][1] + bv);
        float v2 = leakyf(acc2[m][t][2] + bv), v3 = leakyf(acc2[m][t][3] + bv);
        hf[m][t] = pack4(v0, v1, v2, v3);
        cs += v0 + v1 + v2 + v3;
      }
      cs += __shfl_xor(cs, 16);
      cs += __shfl_xor(cs, 32);
      if (kg == 0) pbuf[r * 320 + col] = cs;
    }
    __syncthreads();
    for (int i = tid; i < 320; i += 256) mvec[i] = (pbuf[i] + pbuf[320 + i]) * invLen;
    __syncthreads();

    // ============ group MLP (GEMV, f32 weights) ============
    for (int j = tid; j < 640; j += 256)
      tvec[j] = leakyf(dotW(Wg1l + (size_t)j * 320, mvec, 80) + gb1[l * 640 + j]);
    __syncthreads();
    for (int u = tid; u < 640; u += 256) {
      int j = u >> 1, hh = u & 1;
      pbuf[u] = dotW(Wg2l + (size_t)j * 640 + hh * 320, tvec + hh * 320, 80);
    }
    __syncthreads();
    for (int i = tid; i < 320; i += 256)
      gvec[i] = leakyf(pbuf[2 * i] + pbuf[2 * i + 1] + gb2[l * 320 + i]);
    __syncthreads();
    for (int u = tid; u < 640; u += 256) {
      int j = u >> 1, hh = u & 1;
      pbuf[u] = dotW(Wg3l + (size_t)j * 320 + hh * 160, gvec + hh * 160, 40);
    }
    __syncthreads();
    for (int i = tid; i < 320; i += 256)
      tvec[i] = pbuf[2 * i] + pbuf[2 * i + 1] + cb[l * 320 + i];
    __syncthreads();

    // ============ combine: acc3 = h @ cW_top, h streamed hf->pane ============
    f32x4 acc3[4][10];
#pragma unroll
    for (int m = 0; m < 4; ++m)
#pragma unroll
      for (int t = 0; t < 10; ++t) acc3[m][t] = {0.f, 0.f, 0.f, 0.f};
#pragma unroll
    for (int ks = 0; ks < 5; ++ks) {
      short* pn = pane[ks & 1];
      // chunk ks holds h cols ks*64..+63 = wave tiles t=2ks (local wc), t=2ks+1 (local wc+2)
      const int pc0 = (wc * 16 + i16) * 2;
      const int pc1 = ((wc + 2) * 16 + i16) * 2;
#pragma unroll
      for (int m = 0; m < 4; ++m) {
        scat4(pn, r64 + m * 16 + kg * 4, pc0, hf[m][2 * ks]);
        scat4(pn, r64 + m * 16 + kg * 4, pc1, hf[m][2 * ks + 1]);
      }
      __syncthreads();
#pragma unroll
      for (int kk = 0; kk < 2; ++kk) {
        const int off = (kk * 32 + kg * 8) * 2;
        bf16x8 a[4];
#pragma unroll
        for (int m = 0; m < 4; ++m) a[m] = ldsRow(pn, r64 + m * 16 + i16, off);
        bf16x8 b[10];
#pragma unroll
        for (int t = 0; t < 10; ++t)
          b[t] = gfrag(W4l, ((ks * 20 + wc + 2 * t) * 8 + kk * 4 + kg) * 16 + i16);
#pragma unroll
        for (int m = 0; m < 4; ++m)
#pragma unroll
          for (int t = 0; t < 10; ++t) acc3[m][t] = MFMA_BF16(a[m], b[t], acc3[m][t], 0, 0, 0);
      }
    }

    // epilogue: out = leaky(acc3 + gAdd) + out  (inline RMW on Abuf)
#pragma unroll
    for (int t = 0; t < 10; ++t) {
      const int gt  = wc + 2 * t;
      const int sub = gt >> 2;
      const int lcol2 = ((gt & 3) * 16 + i16) * 2;
      const float ga = tvec[gt * 16 + i16];
      float cs = 0.f;
#pragma unroll
      for (int m = 0; m < 4; ++m) {
        const int row0 = r64 + m * 16 + kg * 4;
        ushort4 ov = gath4(Abuf[sub], row0, lcol2);
        float v0 = leakyf(acc3[m][t][0] + ga) + b2f(ov.x);
        float v1 = leakyf(acc3[m][t][1] + ga) + b2f(ov.y);
        float v2 = leakyf(acc3[m][t][2] + ga) + b2f(ov.z);
        float v3 = leakyf(acc3[m][t][3] + ga) + b2f(ov.w);
        scat4(Abuf[sub], row0, lcol2, pack4(v0, v1, v2, v3));
        cs += v0 + v1 + v2 + v3;
      }
      if (l == 2) {
        cs += __shfl_xor(cs, 16);
        cs += __shfl_xor(cs, 32);
        if (kg == 0) pbuf[r * 320 + gt * 16 + i16] = cs;
      }
    }
  }

  // ============ final head ============
  __syncthreads();
  for (int i = tid; i < 320; i += 256) mvec[i] = (pbuf[i] + pbuf[320 + i]) * invLen;
  __syncthreads();
  for (int j = tid; j < 640; j += 256)
    tvec[j] = leakyf(dotW(Wo1 + (size_t)j * 320, mvec, 80) + ob1[j]);
  __syncthreads();
  float part = 0.f;
  for (int j = tid; j < 640; j += 256) part += tvec[j] * oW2[j];
#pragma unroll
  for (int off = 32; off > 0; off >>= 1) part += __shfl_down(part, off);
  if (lane == 0) redH[wave] = part;
  __syncthreads();
  if (tid == 0) {
    float s = redH[0] + redH[1] + redH[2] + redH[3];
    yout[g] = leakyf(s + ob2[0]) + wsc[0] * log2f((float)lengths[g]);
  }
}

// ---------------------------------------------------------------------------
extern "C" void kernel_launch(void* const* d_in, const int* in_sizes, int n_in,
                              void* d_out, int out_size, void* d_ws, size_t ws_size,
                              hipStream_t stream) {
  const int*   words   = (const int*)  d_in[0];
  const int*   lengths = (const int*)  d_in[1];
  // d_in[2] seg2all: contiguous groups (repeat(arange(B),128)) -> group = row/128
  const float* embedw  = (const float*)d_in[3];
  const float* pu_W1   = (const float*)d_in[4];
  const float* pu_b1   = (const float*)d_in[5];
  const float* pu_W2   = (const float*)d_in[6];
  const float* pu_b2   = (const float*)d_in[7];
  const float* gu_W1   = (const float*)d_in[8];
  const float* gu_b1   = (const float*)d_in[9];
  const float* gu_W2   = (const float*)d_in[10];
  const float* gu_b2   = (const float*)d_in[11];
  const float* c_W     = (const float*)d_in[12];
  const float* c_b     = (const float*)d_in[13];
  const float* o_W1    = (const float*)d_in[14];
  const float* o_b1    = (const float*)d_in[15];
  const float* o_W2    = (const float*)d_in[16];
  const float* o_b2    = (const float*)d_in[17];
  const float* wscal   = (const float*)d_in[18];

  const int B = in_sizes[1];

  size_t off = 0;
  auto alloc = [&](size_t bytes) -> void* {
    void* p = (char*)d_ws + off;
    off += (bytes + 255) & ~(size_t)255;
    return p;
  };
  bf16*  W0  = (bf16*) alloc((size_t)614400 * 2);
  bf16*  W1t = (bf16*) alloc((size_t)614400 * 2);
  bf16*  W4  = (bf16*) alloc((size_t)307200 * 2);
  float* Wg1 = (float*)alloc((size_t)614400 * 4);
  float* Wg2 = (float*)alloc((size_t)614400 * 4);
  float* Wg3 = (float*)alloc((size_t)307200 * 4);
  float* Wo1 = (float*)alloc((size_t)204800 * 4);

  pack_tiles<<<dim3(100, 9), 256, 0, stream>>>(pu_W1, pu_W2, c_W, W0, W1t, W4);
  pack_nmaj<<<dim3(200, 10), 256, 0, stream>>>(gu_W1, gu_W2, c_W, o_W1,
                                               Wg1, Wg2, Wg3, Wo1);
  fused_k<<<B, 256, 0, stream>>>(words, lengths, embedw, W0, W1t, W4,
                                 Wg1, Wg2, Wg3, Wo1,
                                 pu_b1, pu_b2, gu_b1, gu_b2, c_b, o_b1,
                                 o_W2, o_b2, wscal, (float*)d_out);
}

// Round 7
// 933.573 us; speedup vs baseline: 1.1608x; 1.1608x over previous
//
#include <hip/hip_runtime.h>
#include <hip/hip_bf16.h>

using bf16 = __hip_bfloat16;
typedef short bf16x8 __attribute__((ext_vector_type(8)));
typedef float f32x4  __attribute__((ext_vector_type(4)));
typedef unsigned short u16;

__device__ __forceinline__ float leakyf(float x) { return x >= 0.f ? x : 0.01f * x; }

__device__ __forceinline__ float b2f(u16 u) {
  union { unsigned int i; float f; } c; c.i = (unsigned int)u << 16; return c.f;
}
__device__ __forceinline__ u16 f2b(float f) {
  __hip_bfloat16 h = __float2bfloat16(f);
  return *reinterpret_cast<u16*>(&h);
}
__device__ __forceinline__ ushort4 pack4(float a, float b, float c, float d) {
  ushort4 u; u.x = f2b(a); u.y = f2b(b); u.z = f2b(c); u.w = f2b(d); return u;
}

// B-fragment straight from global (prepacked granule order): one dwordx4/lane
__device__ __forceinline__ bf16x8 gfrag(const bf16* __restrict__ p, int gran) {
  return *(const bf16x8*)(p + ((size_t)gran << 3));
}
// A-fragment from XOR-swizzled [128][64] bf16 sub-pane (stride 128 B)
__device__ __forceinline__ bf16x8 ldsRow(const short* buf, int row, int off) {
  return *(const bf16x8*)((const char*)buf + row * 128 + (off ^ ((row & 7) << 4)));
}
// scatter/gather one C-frag column quad (4 consecutive rows), swizzled pane
__device__ __forceinline__ void scat4(short* base, int row0, int col2, ushort4 q) {
  *(u16*)((char*)base + (row0 + 0) * 128 + (col2 ^ (((row0 + 0) & 7) << 4))) = q.x;
  *(u16*)((char*)base + (row0 + 1) * 128 + (col2 ^ (((row0 + 1) & 7) << 4))) = q.y;
  *(u16*)((char*)base + (row0 + 2) * 128 + (col2 ^ (((row0 + 2) & 7) << 4))) = q.z;
  *(u16*)((char*)base + (row0 + 3) * 128 + (col2 ^ (((row0 + 3) & 7) << 4))) = q.w;
}
__device__ __forceinline__ ushort4 gath4(const short* base, int row0, int col2) {
  ushort4 q;
  q.x = *(const u16*)((const char*)base + (row0 + 0) * 128 + (col2 ^ (((row0 + 0) & 7) << 4)));
  q.y = *(const u16*)((const char*)base + (row0 + 1) * 128 + (col2 ^ (((row0 + 1) & 7) << 4)));
  q.z = *(const u16*)((const char*)base + (row0 + 2) * 128 + (col2 ^ (((row0 + 2) & 7) << 4)));
  q.w = *(const u16*)((const char*)base + (row0 + 3) * 128 + (col2 ^ (((row0 + 3) & 7) << 4)));
  return q;
}

// f32 dot: w from global (L2-resident), x from LDS, K4 = K/4
__device__ __forceinline__ float dotW(const float* __restrict__ w,
                                      const float* __restrict__ x, int K4) {
  float s = 0.f;
#pragma unroll 4
  for (int i = 0; i < K4; ++i) {
    float4 wv = *(const float4*)(w + i * 4);
    s += wv.x * x[i * 4 + 0] + wv.y * x[i * 4 + 1] +
         wv.z * x[i * 4 + 2] + wv.w * x[i * 4 + 3];
  }
  return s;
}

// ---------------------------------------------------------------------------
// MFMA weight prepack: fp32 [K][Nc] row-major -> bf16 fragment granules
// granule f = ((ks*NTN + nt)*8 + ch)*16 + i holds cols nt*16+i, k = ks*64+ch*8..+7
// ---------------------------------------------------------------------------
__global__ void pack_tiles(const float* __restrict__ pu1, const float* __restrict__ pu2,
                           const float* __restrict__ cw,
                           bf16* __restrict__ W0, bf16* __restrict__ W1t,
                           bf16* __restrict__ W4) {
  int job = blockIdx.y, type = job / 3, l = job % 3;
  int f = blockIdx.x * 256 + threadIdx.x;
  const float* s; bf16* d; int ld, nch, ntn;
  if (type == 0)      { nch = 25600; s = pu1 + (size_t)l * 204800; d = W0  + (size_t)l * 204800; ld = 640; ntn = 40; }
  else if (type == 1) { nch = 25600; s = pu2 + (size_t)l * 204800; d = W1t + (size_t)l * 204800; ld = 320; ntn = 20; }
  else                { nch = 12800; s = cw  + (size_t)l * 204800; d = W4  + (size_t)l * 102400; ld = 320; ntn = 20; }
  if (f >= nch) return;
  int i = f & 15, ch = (f >> 4) & 7, nt = (f >> 7) % ntn, ks = (f >> 7) / ntn;
  int k = ks * 64 + ch * 8, col = nt * 16 + i;
  bf16x8 v;
#pragma unroll
  for (int j = 0; j < 8; ++j)
    v[j] = (short)f2b(s[(size_t)(k + j) * ld + col]);
  *(bf16x8*)(d + (size_t)f * 8) = v;
}

// ---------------------------------------------------------------------------
// GEMV weight prepack (n-major, f32): out[n][k] = src[k][n]
// jobs 0-2 Wg1 (gu_W1 K320 N640) 3-5 Wg2 (gu_W2 K640 N320)
//      6-8 Wg3 (c_W rows 320.. K320 N320) 9 Wo1 (o_W1 K320 N640)
// ---------------------------------------------------------------------------
__global__ void pack_nmaj(const float* __restrict__ gu1, const float* __restrict__ gu2,
                          const float* __restrict__ cw, const float* __restrict__ ow1,
                          float* __restrict__ Wg1, float* __restrict__ Wg2,
                          float* __restrict__ Wg3, float* __restrict__ Wo1) {
  int job = blockIdx.y;
  int f = blockIdx.x * 256 + threadIdx.x;
  const float* s; float* d; int K, ld, nch, koff = 0;
  if (job < 3)      { int l = job;     K = 320; ld = 640; nch = 51200; s = gu1 + (size_t)l * 204800; d = Wg1 + (size_t)l * 204800; }
  else if (job < 6) { int l = job - 3; K = 640; ld = 320; nch = 51200; s = gu2 + (size_t)l * 204800; d = Wg2 + (size_t)l * 204800; }
  else if (job < 9) { int l = job - 6; K = 320; ld = 320; nch = 25600; s = cw  + (size_t)l * 204800; d = Wg3 + (size_t)l * 102400; koff = 320; }
  else              {                  K = 320; ld = 640; nch = 51200; s = ow1;                      d = Wo1; }
  if (f >= nch) return;
  int K4 = K >> 2;
  int n = f / K4, kq = f % K4;
  int k = koff + kq * 4;
  float4 v = { s[(size_t)(k + 0) * ld + n], s[(size_t)(k + 1) * ld + n],
               s[(size_t)(k + 2) * ld + n], s[(size_t)(k + 3) * ld + n] };
  *(float4*)(d + (size_t)f * 4) = v;
}

#define MFMA_BF16 __builtin_amdgcn_mfma_f32_16x16x32_bf16

// ---------------------------------------------------------------------------
// Fused per-group network. Block = 1 group (128 rows), 512 thr = 8 waves (2r x 4c).
// Per-layer phase ORDER is chosen so no activation array crosses the GEMV phase:
//   1) point-MLP (acc2) -> hf regs   2) combine MFMA (hf -> pane -> acc3), hf dies
//   3) GEMV (only acc3 accumulators live, accum-side)   4) epilogue RMW on Abuf.
// Abuf[5][128][64]: resident `out` (bf16, XOR-swizzled). pane[2]: h1/h chunks.
// All MFMA B-operands load as granules directly from L2 (prepacked order).
// ---------------------------------------------------------------------------
__global__ __launch_bounds__(512, 1)
void fused_k(const int* __restrict__ words, const int* __restrict__ lengths,
             const float* __restrict__ embed,
             const bf16* __restrict__ W0, const bf16* __restrict__ W1t,
             const bf16* __restrict__ W4,
             const float* __restrict__ Wg1, const float* __restrict__ Wg2,
             const float* __restrict__ Wg3, const float* __restrict__ Wo1,
             const float* __restrict__ pb1, const float* __restrict__ pb2,
             const float* __restrict__ gb1, const float* __restrict__ gb2,
             const float* __restrict__ cb,  const float* __restrict__ ob1,
             const float* __restrict__ oW2, const float* __restrict__ ob2,
             const float* __restrict__ wsc, float* __restrict__ yout)
{
  __shared__ short Abuf[5][8192];   // 80 KB resident out
  __shared__ short pane[2][8192];   // 32 KB h1/h chunk dbuf
  __shared__ int   wrdL[640];
  __shared__ float mvec[320], gvec[320];
  __shared__ float tvec[640], pbuf[640];
  __shared__ float redH[8];

  const int g    = blockIdx.x;
  const int tid  = threadIdx.x;
  const int wave = tid >> 6, lane = tid & 63;
  const int r    = wave >> 2, wc = wave & 3;   // 2 row-waves x 4 col-waves
  const int i16  = lane & 15, kg = lane >> 4;
  const int r64  = r * 64;
  const int pcol2 = (wc * 16 + i16) * 2;
  const float invLen = 1.0f / (float)lengths[g];

  for (int i = tid; i < 640; i += 512) wrdL[i] = words[(size_t)g * 640 + i];
  __syncthreads();

  // ---- init Abuf = embedded points (bf16, swizzled sub-panes) ----
#pragma unroll
  for (int q = 0; q < 10; ++q) {
    int f = q * 512 + tid;               // 5120 chunks: 128 rows x 40 col-chunks
    int row = f / 40, cc = f - row * 40;
    int sub = cc >> 3, lc = cc & 7;
    int col0 = cc * 8;
    int w = wrdL[row * 5 + (col0 >> 6)];
    const float* ep = embed + (size_t)w * 64 + (col0 & 63);
    bf16x8 v;
#pragma unroll
    for (int u = 0; u < 8; ++u) v[u] = (short)f2b(ep[u]);
    *(bf16x8*)((char*)(Abuf[sub]) + row * 128 + ((lc * 16) ^ ((row & 7) << 4))) = v;
  }

  for (int l = 0; l < 3; ++l) {
    const bf16*  W0l  = W0  + (size_t)l * 204800;
    const bf16*  W1l  = W1t + (size_t)l * 204800;
    const bf16*  W4l  = W4  + (size_t)l * 102400;
    const float* Wg1l = Wg1 + (size_t)l * 204800;
    const float* Wg2l = Wg2 + (size_t)l * 204800;
    const float* Wg3l = Wg3 + (size_t)l * 102400;

    __syncthreads();   // Abuf writes (embed / prev epilogue) + pane reuse safe

    // ============ 1) point MLP: 10 chunks, GEMM1 -> pane -> GEMM2 ============
    f32x4 acc2[4][5];
#pragma unroll
    for (int m = 0; m < 4; ++m)
#pragma unroll
      for (int t = 0; t < 5; ++t) acc2[m][t] = {0.f, 0.f, 0.f, 0.f};

    for (int c = 0; c < 10; ++c) {
      short* pn = pane[c & 1];
      // GEMM1: tile (4c+wc) of h1 = leaky(out @ W0 + b1)
      f32x4 acc1[4];
#pragma unroll
      for (int m = 0; m < 4; ++m) acc1[m] = {0.f, 0.f, 0.f, 0.f};
#pragma unroll
      for (int ks = 0; ks < 5; ++ks) {
#pragma unroll
        for (int kk = 0; kk < 2; ++kk) {
          const int off = (kk * 32 + kg * 8) * 2;
          bf16x8 a[4];
#pragma unroll
          for (int m = 0; m < 4; ++m) a[m] = ldsRow(Abuf[ks], r64 + m * 16 + i16, off);
          bf16x8 b = gfrag(W0l, ((ks * 40 + c * 4 + wc) * 8 + kk * 4 + kg) * 16 + i16);
#pragma unroll
          for (int m = 0; m < 4; ++m) acc1[m] = MFMA_BF16(a[m], b, acc1[m], 0, 0, 0);
        }
      }
      {
        const float bv = pb1[l * 640 + c * 64 + wc * 16 + i16];
#pragma unroll
        for (int m = 0; m < 4; ++m)
          scat4(pn, r64 + m * 16 + kg * 4, pcol2,
                pack4(leakyf(acc1[m][0] + bv), leakyf(acc1[m][1] + bv),
                      leakyf(acc1[m][2] + bv), leakyf(acc1[m][3] + bv)));
      }
      __syncthreads();                 // pane chunk ready (dbuf keeps 1 bar safe)
      // GEMM2 accumulate: k-slice c
#pragma unroll
      for (int kk = 0; kk < 2; ++kk) {
        const int off = (kk * 32 + kg * 8) * 2;
        bf16x8 a[4];
#pragma unroll
        for (int m = 0; m < 4; ++m) a[m] = ldsRow(pn, r64 + m * 16 + i16, off);
        bf16x8 b[5];
#pragma unroll
        for (int t = 0; t < 5; ++t)
          b[t] = gfrag(W1l, ((c * 20 + wc + 4 * t) * 8 + kk * 4 + kg) * 16 + i16);
#pragma unroll
        for (int m = 0; m < 4; ++m)
#pragma unroll
          for (int t = 0; t < 5; ++t) acc2[m][t] = MFMA_BF16(a[m], b[t], acc2[m][t], 0, 0, 0);
      }
    }

    // ---- h epilogue: pack hf + column sums -> pbuf ----
    ushort4 hf[4][5];
#pragma unroll
    for (int t = 0; t < 5; ++t) {
      const int col = (wc + 4 * t) * 16 + i16;
      const float bv = pb2[l * 320 + col];
      float cs = 0.f;
#pragma unroll
      for (int m = 0; m < 4; ++m) {
        float v0 = leakyf(acc2[m][t][0] + bv), v1 = leakyf(acc2[m][t][1] + bv);
        float v2 = leakyf(acc2[m][t][2] + bv), v3 = leakyf(acc2[m][t][3] + bv);
        hf[m][t] = pack4(v0, v1, v2, v3);
        cs += v0 + v1 + v2 + v3;
      }
      cs += __shfl_xor(cs, 16);
      cs += __shfl_xor(cs, 32);
      if (kg == 0) pbuf[r * 320 + col] = cs;
    }
    __syncthreads();
    for (int i = tid; i < 320; i += 512) mvec[i] = (pbuf[i] + pbuf[320 + i]) * invLen;

    // ============ 2) combine MFMA: acc3 = h @ cW_top (hf -> pane) ============
    // (independent of GEMV; runs first so hf dies before the GEMV phase)
    f32x4 acc3[4][5];
#pragma unroll
    for (int m = 0; m < 4; ++m)
#pragma unroll
      for (int t = 0; t < 5; ++t) acc3[m][t] = {0.f, 0.f, 0.f, 0.f};
#pragma unroll
    for (int ks = 0; ks < 5; ++ks) {
      short* pn = pane[ks & 1];
#pragma unroll
      for (int m = 0; m < 4; ++m)
        scat4(pn, r64 + m * 16 + kg * 4, pcol2, hf[m][ks]);
      __syncthreads();                 // also makes mvec visible before GEMV
#pragma unroll
      for (int kk = 0; kk < 2; ++kk) {
        const int off = (kk * 32 + kg * 8) * 2;
        bf16x8 a[4];
#pragma unroll
        for (int m = 0; m < 4; ++m) a[m] = ldsRow(pn, r64 + m * 16 + i16, off);
        bf16x8 b[5];
#pragma unroll
        for (int t = 0; t < 5; ++t)
          b[t] = gfrag(W4l, ((ks * 20 + wc + 4 * t) * 8 + kk * 4 + kg) * 16 + i16);
#pragma unroll
        for (int m = 0; m < 4; ++m)
#pragma unroll
          for (int t = 0; t < 5; ++t) acc3[m][t] = MFMA_BF16(a[m], b[t], acc3[m][t], 0, 0, 0);
      }
    }

    // ============ 3) group MLP (GEMV, f32 weights); only acc3 stays live =====
    for (int j = tid; j < 640; j += 512)
      tvec[j] = leakyf(dotW(Wg1l + (size_t)j * 320, mvec, 80) + gb1[l * 640 + j]);
    __syncthreads();
    for (int u = tid; u < 640; u += 512) {
      int j = u >> 1, hh = u & 1;
      pbuf[u] = dotW(Wg2l + (size_t)j * 640 + hh * 320, tvec + hh * 320, 80);
    }
    __syncthreads();
    for (int i = tid; i < 320; i += 512)
      gvec[i] = leakyf(pbuf[2 * i] + pbuf[2 * i + 1] + gb2[l * 320 + i]);
    __syncthreads();
    for (int u = tid; u < 640; u += 512) {
      int j = u >> 1, hh = u & 1;
      pbuf[u] = dotW(Wg3l + (size_t)j * 320 + hh * 160, gvec + hh * 160, 40);
    }
    __syncthreads();
    for (int i = tid; i < 320; i += 512)
      tvec[i] = pbuf[2 * i] + pbuf[2 * i + 1] + cb[l * 320 + i];
    __syncthreads();

    // ============ 4) epilogue: out = leaky(acc3 + gAdd) + out (RMW Abuf) =====
#pragma unroll
    for (int t = 0; t < 5; ++t) {
      const int gt  = wc + 4 * t;
      const int sub = gt >> 2;
      const int lcol2 = ((gt & 3) * 16 + i16) * 2;
      const float ga = tvec[gt * 16 + i16];
      float cs = 0.f;
#pragma unroll
      for (int m = 0; m < 4; ++m) {
        const int row0 = r64 + m * 16 + kg * 4;
        ushort4 ov = gath4(Abuf[sub], row0, lcol2);
        float v0 = leakyf(acc3[m][t][0] + ga) + b2f(ov.x);
        float v1 = leakyf(acc3[m][t][1] + ga) + b2f(ov.y);
        float v2 = leakyf(acc3[m][t][2] + ga) + b2f(ov.z);
        float v3 = leakyf(acc3[m][t][3] + ga) + b2f(ov.w);
        scat4(Abuf[sub], row0, lcol2, pack4(v0, v1, v2, v3));
        cs += v0 + v1 + v2 + v3;
      }
      if (l == 2) {
        cs += __shfl_xor(cs, 16);
        cs += __shfl_xor(cs, 32);
        if (kg == 0) pbuf[r * 320 + gt * 16 + i16] = cs;
      }
    }
  }

  // ============ final head ============
  __syncthreads();
  for (int i = tid; i < 320; i += 512) mvec[i] = (pbuf[i] + pbuf[320 + i]) * invLen;
  __syncthreads();
  for (int j = tid; j < 640; j += 512)
    tvec[j] = leakyf(dotW(Wo1 + (size_t)j * 320, mvec, 80) + ob1[j]);
  __syncthreads();
  float part = 0.f;
  for (int j = tid; j < 640; j += 512) part += tvec[j] * oW2[j];
#pragma unroll
  for (int off = 32; off > 0; off >>= 1) part += __shfl_down(part, off);
  if (lane == 0) redH[wave] = part;
  __syncthreads();
  if (tid == 0) {
    float s = 0.f;
#pragma unroll
    for (int w = 0; w < 8; ++w) s += redH[w];
    yout[g] = leakyf(s + ob2[0]) + wsc[0] * log2f((float)lengths[g]);
  }
}

// ---------------------------------------------------------------------------
extern "C" void kernel_launch(void* const* d_in, const int* in_sizes, int n_in,
                              void* d_out, int out_size, void* d_ws, size_t ws_size,
                              hipStream_t stream) {
  const int*   words   = (const int*)  d_in[0];
  const int*   lengths = (const int*)  d_in[1];
  // d_in[2] seg2all: contiguous groups (repeat(arange(B),128)) -> group = row/128
  const float* embedw  = (const float*)d_in[3];
  const float* pu_W1   = (const float*)d_in[4];
  const float* pu_b1   = (const float*)d_in[5];
  const float* pu_W2   = (const float*)d_in[6];
  const float* pu_b2   = (const float*)d_in[7];
  const float* gu_W1   = (const float*)d_in[8];
  const float* gu_b1   = (const float*)d_in[9];
  const float* gu_W2   = (const float*)d_in[10];
  const float* gu_b2   = (const float*)d_in[11];
  const float* c_W     = (const float*)d_in[12];
  const float* c_b     = (const float*)d_in[13];
  const float* o_W1    = (const float*)d_in[14];
  const float* o_b1    = (const float*)d_in[15];
  const float* o_W2    = (const float*)d_in[16];
  const float* o_b2    = (const float*)d_in[17];
  const float* wscal   = (const float*)d_in[18];

  const int B = in_sizes[1];

  size_t off = 0;
  auto alloc = [&](size_t bytes) -> void* {
    void* p = (char*)d_ws + off;
    off += (bytes + 255) & ~(size_t)255;
    return p;
  };
  bf16*  W0  = (bf16*) alloc((size_t)614400 * 2);
  bf16*  W1t = (bf16*) alloc((size_t)614400 * 2);
  bf16*  W4  = (bf16*) alloc((size_t)307200 * 2);
  float* Wg1 = (float*)alloc((size_t)614400 * 4);
  float* Wg2 = (float*)alloc((size_t)614400 * 4);
  float* Wg3 = (float*)alloc((size_t)307200 * 4);
  float* Wo1 = (float*)alloc((size_t)204800 * 4);

  pack_tiles<<<dim3(100, 9), 256, 0, stream>>>(pu_W1, pu_W2, c_W, W0, W1t, W4);
  pack_nmaj<<<dim3(200, 10), 256, 0, stream>>>(gu_W1, gu_W2, c_W, o_W1,
                                               Wg1, Wg2, Wg3, Wo1);
  fused_k<<<B, 512, 0, stream>>>(words, lengths, embedw, W0, W1t, W4,
                                 Wg1, Wg2, Wg3, Wo1,
                                 pu_b1, pu_b2, gu_b1, gu_b2, c_b, o_b1,
                                 o_W2, o_b2, wscal, (float*)d_out);
}